// Round 1
// baseline (2137.122 us; speedup 1.0000x reference)
//
#include <hip/hip_runtime.h>
#include <math.h>

#define KSZ   11
#define RAD   5
#define TILE  64
#define LDSW  (TILE + 2 * RAD)   // 74 — stride 74 floats (74 % 32 = 10, no pow2 conflicts)
#define NTHREADS 256

// Fused separable Gaussian blur, reflect padding, depthwise (same kernel all channels).
// Tile: 64x64 outputs per block; LDS holds 74x74 input halo tile + 64x74 vertical-pass buffer.
__global__ __launch_bounds__(NTHREADS)
void gauss_blur_kernel(const float* __restrict__ x,
                       const float* __restrict__ sigma,
                       float* __restrict__ out,
                       int H, int W) {
    __shared__ float s_w[KSZ];
    __shared__ float s_in[LDSW * LDSW];    // 74*74 = 5476 floats = 21.9 KB
    __shared__ float s_mid[TILE * LDSW];   // 64*74 = 4736 floats = 18.9 KB

    const int tid = threadIdx.x;

    // Thread 0 computes normalized 1D Gaussian weights from sigma.
    // 2D kernel normalization == (1D normalization) applied twice, since
    // sum2d = (sum1d)^2 for a separable Gaussian.
    if (tid == 0) {
        float s   = fabsf(sigma[0]) + 1e-6f;
        float inv = 1.0f / (2.0f * s * s);
        float tmp[KSZ];
        float sum = 0.0f;
#pragma unroll
        for (int k = 0; k < KSZ; ++k) {
            float r = (float)(k - RAD);
            tmp[k] = expf(-r * r * inv);
            sum += tmp[k];
        }
        float rs = 1.0f / sum;
#pragma unroll
        for (int k = 0; k < KSZ; ++k) s_w[k] = tmp[k] * rs;
    }

    const int  plane = blockIdx.z;                 // b*C + c, 0..1023
    const long base  = (long)plane * H * W;
    const int  tx0   = blockIdx.x * TILE;
    const int  ty0   = blockIdx.y * TILE;

    // ---- Stage 1: global -> LDS, 74x74 halo tile with reflect indexing ----
    for (int idx = tid; idx < LDSW * LDSW; idx += NTHREADS) {
        int r  = idx / LDSW;
        int c  = idx - r * LDSW;
        int gy = ty0 + r - RAD;
        int gx = tx0 + c - RAD;
        // reflect (mode="reflect": -1 -> 1, H -> H-2); pad=5 < H so one fold suffices
        gy = (gy < 0)  ? -gy            : gy;
        gy = (gy >= H) ? (2 * H - 2 - gy) : gy;
        gx = (gx < 0)  ? -gx            : gx;
        gx = (gx >= W) ? (2 * W - 2 - gx) : gx;
        s_in[idx] = x[base + (long)gy * W + gx];
    }
    __syncthreads();   // also publishes s_w

    // ---- Stage 2: vertical 11-tap into s_mid (64 rows x 74 cols) ----
    for (int idx = tid; idx < TILE * LDSW; idx += NTHREADS) {
        int r = idx / LDSW;
        int c = idx - r * LDSW;
        float acc = 0.0f;
#pragma unroll
        for (int k = 0; k < KSZ; ++k)
            acc += s_w[k] * s_in[(r + k) * LDSW + c];
        s_mid[idx] = acc;
    }
    __syncthreads();

    // ---- Stage 3: horizontal 11-tap, coalesced store ----
    for (int idx = tid; idx < TILE * TILE; idx += NTHREADS) {
        int r = idx >> 6;      // / 64
        int c = idx & 63;      // % 64
        float acc = 0.0f;
#pragma unroll
        for (int k = 0; k < KSZ; ++k)
            acc += s_w[k] * s_mid[r * LDSW + c + k];
        out[base + (long)(ty0 + r) * W + (tx0 + c)] = acc;
    }
}

extern "C" void kernel_launch(void* const* d_in, const int* in_sizes, int n_in,
                              void* d_out, int out_size, void* d_ws, size_t ws_size,
                              hipStream_t stream) {
    const float* x     = (const float*)d_in[0];
    const float* sigma = (const float*)d_in[1];
    float*       out   = (float*)d_out;

    const int H = 512, W = 512;
    const int planes = in_sizes[0] / (H * W);   // 16*64 = 1024

    dim3 grid(W / TILE, H / TILE, planes);      // (8, 8, 1024)
    dim3 block(NTHREADS);
    gauss_blur_kernel<<<grid, block, 0, stream>>>(x, sigma, out, H, W);
}